// Round 12
// baseline (377.947 us; speedup 1.0000x reference)
//
#include <hip/hip_runtime.h>
#include <hip/hip_fp16.h>
#include <cstddef>
#include <cstdint>

// N=50000, F_IN=128, HID=64, HEADS=4, E=800000, NG=64
// L1: x(fp32)@W1p -> h1(fp16) + fused als1/ald1 (MFMA epilogue);
//     k_w1: edge weights -> CSR-ordered head-major fp16 planes + selfw + inv;
//     k_edge1s: XCD-sliced gather (slice=b&7 -> 3.2MB/XCD L2-resident) -> x2 fp16
// L2: x2@W2p -> h2(fp16) + fused als2/ald2; GAT agg (R10 8-wide) -> out2 fp32
// Pool: segment-mean; fc.

#define LOG2E 1.4426950408889634f
__device__ __forceinline__ float lrelu02(float x) { return x >= 0.f ? x : 0.2f * x; }
__device__ __forceinline__ float elu1(float x)    { return x > 0.f ? x : expm1f(x); }
__device__ __forceinline__ float fexp(float x)    { return exp2f(x * LOG2E); }

typedef _Float16 f16x8 __attribute__((ext_vector_type(8)));
typedef float    f32x4 __attribute__((ext_vector_type(4)));

// ---------------- CSR build (by destination) ----------------
__global__ void k_hist(const int* __restrict__ dst, int* __restrict__ cnt,
                       int* __restrict__ rank, int e) {
    int i = blockIdx.x * 256 + threadIdx.x;
    if (i < e) rank[i] = atomicAdd(&cnt[dst[i]], 1);
}

__global__ __launch_bounds__(1024) void k_scan1(const int* __restrict__ cnt,
                                                int* __restrict__ cscan,
                                                int* __restrict__ bsum, int n) {
    __shared__ int ws[16];
    const int t = threadIdx.x, lane = t & 63, wv = t >> 6;
    const int i = blockIdx.x * 1024 + t;
    int v = (i < n) ? cnt[i] : 0;
    int s = v;
#pragma unroll
    for (int d = 1; d < 64; d <<= 1) { int o = __shfl_up(s, d); if (lane >= d) s += o; }
    if (lane == 63) ws[wv] = s;
    __syncthreads();
    if (t < 16) {
        int xx = ws[t];
#pragma unroll
        for (int d = 1; d < 16; d <<= 1) { int o = __shfl_up(xx, d); if (t >= d) xx += o; }
        ws[t] = xx;
        if (t == 15) bsum[blockIdx.x] = xx;
    }
    __syncthreads();
    int incl = s + (wv > 0 ? ws[wv - 1] : 0);
    if (i < n) cscan[i] = incl;
}

__global__ __launch_bounds__(1024) void k_scan2(int* __restrict__ bsum, int nb) {
    __shared__ int ws[16];
    const int t = threadIdx.x, lane = t & 63, wv = t >> 6;
    int v = (t < nb) ? bsum[t] : 0;
    int s = v;
#pragma unroll
    for (int d = 1; d < 64; d <<= 1) { int o = __shfl_up(s, d); if (lane >= d) s += o; }
    if (lane == 63) ws[wv] = s;
    __syncthreads();
    if (t < 16) {
        int xx = ws[t];
#pragma unroll
        for (int d = 1; d < 16; d <<= 1) { int o = __shfl_up(xx, d); if (t >= d) xx += o; }
        ws[t] = xx;
    }
    __syncthreads();
    int incl = s + (wv > 0 ? ws[wv - 1] : 0);
    if (t < nb) bsum[t] = incl - v;   // exclusive
}

__global__ __launch_bounds__(1024) void k_scan3(const int* __restrict__ cscan,
                                                const int* __restrict__ bsum,
                                                int* __restrict__ rowptr, int n) {
    const int i = blockIdx.x * 1024 + threadIdx.x;
    if (i < n) rowptr[i + 1] = cscan[i] + bsum[blockIdx.x];
    if (i == 0) rowptr[0] = 0;
}

__global__ void k_scatter(const int* __restrict__ src, const int* __restrict__ dstArr,
                          const int* __restrict__ rank, const int* __restrict__ rowptr,
                          int* __restrict__ csr, int e) {
    int i = blockIdx.x * 256 + threadIdx.x;
    if (i < e) csr[rowptr[dstArr[i]] + rank[i]] = src[i];
}

// ---------------- W pack (both weights in one launch) ----------------
__device__ __forceinline__ void packOne(const float* __restrict__ W, __half* __restrict__ Bp,
                                        int K, int N, int i) {
    int c = i & 15, q = (i >> 4) & 3, tnt = i >> 6;
    int nt = tnt % (N / 16), t = tnt / (N / 16);
    int k0 = t * 32 + q * 8, col = nt * 16 + c;
    __half tmp[8];
#pragma unroll
    for (int j = 0; j < 8; ++j) tmp[j] = __float2half(W[(size_t)(k0 + j) * N + col]);
    *reinterpret_cast<int4*>(Bp + (size_t)i * 8) = *reinterpret_cast<int4*>(tmp);
}

__global__ void k_packW(const float* __restrict__ W1, __half* __restrict__ B1,
                        const float* __restrict__ W2, __half* __restrict__ B2) {
    int i = blockIdx.x * 256 + threadIdx.x;
    if (i < 4096) packOne(W1, B1, 128, 256, i);
    else if (i < 4096 + 2048) packOne(W2, B2, 256, 64, i - 4096);
}

// ---------------- MFMA GEMM + fused attention logits ----------------
template <int K, int N, bool AF32, int HEADS_>
__global__ __launch_bounds__(256) void k_gemm_mfma(const void* __restrict__ Av,
                                                   const __half* __restrict__ Bp,
                                                   __half* __restrict__ C,
                                                   const float* __restrict__ a_src,
                                                   const float* __restrict__ a_dst,
                                                   float* __restrict__ als,
                                                   float* __restrict__ ald, int M) {
    constexpr int NT = N / 16, KT = K / 32;
    const int lane = threadIdx.x & 63;
    const int wv = threadIdx.x >> 6;
    const int row0 = (blockIdx.x * 4 + wv) * 16;
    if (row0 >= M) return;

    f32x4 acc[NT];
#pragma unroll
    for (int nt = 0; nt < NT; ++nt) acc[nt] = (f32x4){0.f, 0.f, 0.f, 0.f};

    const __half* Ah = (const __half*)Av;
    const float*  Af = (const float*)Av;
    const size_t arow = (size_t)(row0 + (lane & 15)) * K + (lane >> 4) * 8;
    const __half* Bb = Bp + (size_t)lane * 8;
#pragma unroll
    for (int t = 0; t < KT; ++t) {
        f16x8 a;
        if constexpr (AF32) {
            float4 u0 = *reinterpret_cast<const float4*>(Af + arow + t * 32);
            float4 u1 = *reinterpret_cast<const float4*>(Af + arow + t * 32 + 4);
            a[0] = (_Float16)u0.x; a[1] = (_Float16)u0.y;
            a[2] = (_Float16)u0.z; a[3] = (_Float16)u0.w;
            a[4] = (_Float16)u1.x; a[5] = (_Float16)u1.y;
            a[6] = (_Float16)u1.z; a[7] = (_Float16)u1.w;
        } else {
            a = *reinterpret_cast<const f16x8*>(Ah + arow + t * 32);
        }
#pragma unroll
        for (int nt = 0; nt < NT; ++nt) {
            f16x8 b = *reinterpret_cast<const f16x8*>(Bb + (size_t)(t * NT + nt) * 512);
            acc[nt] = __builtin_amdgcn_mfma_f32_16x16x32_f16(a, b, acc[nt], 0, 0, 0);
        }
    }
    const int r0 = row0 + (lane >> 4) * 4;
    const int cl = lane & 15;
#pragma unroll
    for (int nt = 0; nt < NT; ++nt) {
        int col = nt * 16 + cl;
#pragma unroll
        for (int j = 0; j < 4; ++j)
            C[(size_t)(r0 + j) * N + col] = __float2half(acc[nt][j]);
    }
    float av[NT], dv[NT];
#pragma unroll
    for (int nt = 0; nt < NT; ++nt) {
        av[nt] = a_src[nt * 16 + cl];
        dv[nt] = a_dst[nt * 16 + cl];
    }
    constexpr int NTH = NT / HEADS_;
#pragma unroll
    for (int j = 0; j < 4; ++j) {
#pragma unroll
        for (int h = 0; h < HEADS_; ++h) {
            float ps = 0.f, pd = 0.f;
#pragma unroll
            for (int t = 0; t < NTH; ++t) {
                ps = fmaf(acc[h * NTH + t][j], av[h * NTH + t], ps);
                pd = fmaf(acc[h * NTH + t][j], dv[h * NTH + t], pd);
            }
#pragma unroll
            for (int d = 1; d < 16; d <<= 1) { ps += __shfl_xor(ps, d); pd += __shfl_xor(pd, d); }
            if (cl == 0) {
                int r = r0 + j;
                als[(size_t)r * HEADS_ + h] = ps;
                ald[(size_t)r * HEADS_ + h] = pd;
            }
        }
    }
}

// ---------------- layer-1 edge weights: CSR-ordered, head-major planes ----------------
// Wave per node; lanes 0-31: e8=lane&7 (edge slot), h8=(lane>>3)&3 (head).
// Writes wbuf[h*epad + p] fp16, selfw[node*4+h] fp16, inv1[node*4+h] = 1/(wsum+eps).
__global__ void k_w1(const float* __restrict__ als, const float* __restrict__ ald,
                     const int* __restrict__ rowptr, const int* __restrict__ csr,
                     __half* __restrict__ wbuf, __half* __restrict__ selfw,
                     float* __restrict__ inv1, int n, int epad) {
    const int lane = threadIdx.x & 63;
    const int node = (blockIdx.x << 2) + (threadIdx.x >> 6);
    if (node >= n) return;
    const bool lo = lane < 32;
    const int e8 = lane & 7, h8 = (lane >> 3) & 3;
    const float adh = ald[node * 4 + h8];
    const int beg = rowptr[node];
    const int deg = rowptr[node + 1] - beg;
    float wsum = 0.f;
    for (int base = 0; base < deg; base += 8) {
        float w = 0.f;
        if (lo && base + e8 < deg) {
            int se = csr[beg + base + e8];
            w = fexp(lrelu02(als[(size_t)se * 4 + h8] + adh));
            wbuf[(size_t)h8 * epad + beg + base + e8] = __float2half(w);
        }
        wsum += w;
    }
    // self-loop weight
    float ws = fexp(lrelu02(als[node * 4 + h8] + adh));
    if (lo && e8 == 0) {
        selfw[node * 4 + h8] = __float2half(ws);
        wsum += ws;
    }
#pragma unroll
    for (int d = 1; d < 8; d <<= 1) wsum += __shfl_xor(wsum, d);
    if (lo && e8 == 0) inv1[node * 4 + h8] = 1.f / (wsum + 1e-16f);
}

// ---------------- edge aggregation, layer 1 — XCD-sliced ----------------
// slice = blockIdx&7 -> lands on XCD (blockIdx%8): each XCD touches only a 64B
// (32-ch) slice of every h1 row => 3.2MB working set, L2-resident.
// Wave = (node, slice). Lanes: chl=lane&31 (channel), eslot=lane>>5 (2 edges/load).
__global__ void k_edge1s(const __half* __restrict__ h1, const __half* __restrict__ wbuf,
                         const __half* __restrict__ selfw, const float* __restrict__ inv1,
                         const int* __restrict__ rowptr, const int* __restrict__ csr,
                         const float* __restrict__ b1, __half* __restrict__ x2,
                         int n, int epad) {
    const int lane = threadIdx.x & 63;
    const int slice = blockIdx.x & 7;
    const int node = (blockIdx.x >> 3) * 4 + (threadIdx.x >> 6);
    if (node >= n) return;
    const int head = slice >> 1;
    const int chl = lane & 31;
    const int eslot = lane >> 5;
    const int e8 = lane & 7;
    const __half* hb = h1 + slice * 32 + chl;
    const int beg = rowptr[node];
    const int deg = rowptr[node + 1] - beg;
    const float wself = __half2float(selfw[node * 4 + head]);
    float acc = 0.f;
    for (int base = 0; base <= deg; base += 8) {
        // wave-uniform csr loads -> scalars (slot >= deg maps to self node)
        int s0 = (base + 0 < deg) ? csr[beg + base + 0] : node;
        int s1 = (base + 1 < deg) ? csr[beg + base + 1] : node;
        int s2 = (base + 2 < deg) ? csr[beg + base + 2] : node;
        int s3 = (base + 3 < deg) ? csr[beg + base + 3] : node;
        int s4 = (base + 4 < deg) ? csr[beg + base + 4] : node;
        int s5 = (base + 5 < deg) ? csr[beg + base + 5] : node;
        int s6 = (base + 6 < deg) ? csr[beg + base + 6] : node;
        int s7 = (base + 7 < deg) ? csr[beg + base + 7] : node;
        // weight for slot base+e8 from the precomputed plane (or self / 0)
        float myw;
        if (base + e8 < deg)       myw = __half2float(wbuf[(size_t)head * epad + beg + base + e8]);
        else if (base + e8 == deg) myw = wself;
        else                       myw = 0.f;
        // 4 pair-loads: lane reads 2B of row s[2p+eslot] at its slice channel
        int p0 = eslot ? s1 : s0;
        int p1 = eslot ? s3 : s2;
        int p2 = eslot ? s5 : s4;
        int p3 = eslot ? s7 : s6;
        float v0 = __half2float(hb[(size_t)p0 * 256]);
        float v1 = __half2float(hb[(size_t)p1 * 256]);
        float v2 = __half2float(hb[(size_t)p2 * 256]);
        float v3 = __half2float(hb[(size_t)p3 * 256]);
        float w0 = __shfl(myw, 0 + eslot);
        float w1 = __shfl(myw, 2 + eslot);
        float w2 = __shfl(myw, 4 + eslot);
        float w3 = __shfl(myw, 6 + eslot);
        acc = fmaf(w0, v0, acc);
        acc = fmaf(w1, v1, acc);
        acc = fmaf(w2, v2, acc);
        acc = fmaf(w3, v3, acc);
    }
    acc += __shfl_xor(acc, 32);
    if (eslot == 0) {
        float o = elu1(acc * inv1[node * 4 + head] + b1[slice * 32 + chl]);
        x2[(size_t)node * 256 + slice * 32 + chl] = __float2half(o);
    }
}

// ---------------- edge aggregation, layer 2 (R10 masked 8-wide) ----------------
__global__ void k_edge2(const __half* __restrict__ h2, const float* __restrict__ als,
                        const float* __restrict__ ald, const int* __restrict__ rowptr,
                        const int* __restrict__ csr, const float* __restrict__ b2,
                        float* __restrict__ out2, int n) {
    const int lane = threadIdx.x & 63;
    const int node = (blockIdx.x << 2) + (threadIdx.x >> 6);
    if (node >= n) return;
    const int e8 = lane & 7;
    const float adl = ald[node];
    float accA = 0.f, accB = 0.f, wsum = 0.f;
    const int beg = rowptr[node];
    const int deg = rowptr[node + 1] - beg;
    for (int base = 0; base <= deg; base += 8) {
        int s0 = (base + 0 < deg) ? csr[beg + base + 0] : node;
        int s1 = (base + 1 < deg) ? csr[beg + base + 1] : node;
        int s2 = (base + 2 < deg) ? csr[beg + base + 2] : node;
        int s3 = (base + 3 < deg) ? csr[beg + base + 3] : node;
        int s4 = (base + 4 < deg) ? csr[beg + base + 4] : node;
        int s5 = (base + 5 < deg) ? csr[beg + base + 5] : node;
        int s6 = (base + 6 < deg) ? csr[beg + base + 6] : node;
        int s7 = (base + 7 < deg) ? csr[beg + base + 7] : node;
        float v0 = __half2float(h2[(size_t)s0 * 64 + lane]);
        float v1 = __half2float(h2[(size_t)s1 * 64 + lane]);
        float v2 = __half2float(h2[(size_t)s2 * 64 + lane]);
        float v3 = __half2float(h2[(size_t)s3 * 64 + lane]);
        float v4 = __half2float(h2[(size_t)s4 * 64 + lane]);
        float v5 = __half2float(h2[(size_t)s5 * 64 + lane]);
        float v6 = __half2float(h2[(size_t)s6 * 64 + lane]);
        float v7 = __half2float(h2[(size_t)s7 * 64 + lane]);
        int se = s0;
        se = (e8 == 1) ? s1 : se; se = (e8 == 2) ? s2 : se; se = (e8 == 3) ? s3 : se;
        se = (e8 == 4) ? s4 : se; se = (e8 == 5) ? s5 : se; se = (e8 == 6) ? s6 : se;
        se = (e8 == 7) ? s7 : se;
        float myw = (base + e8 <= deg) ? fexp(lrelu02(als[se] + adl)) : 0.f;
        float w0 = __shfl(myw, 0), w1 = __shfl(myw, 1), w2 = __shfl(myw, 2), w3 = __shfl(myw, 3);
        float w4 = __shfl(myw, 4), w5 = __shfl(myw, 5), w6 = __shfl(myw, 6), w7 = __shfl(myw, 7);
        accA = fmaf(w0, v0, accA); accB = fmaf(w1, v1, accB);
        accA = fmaf(w2, v2, accA); accB = fmaf(w3, v3, accB);
        accA = fmaf(w4, v4, accA); accB = fmaf(w5, v5, accB);
        accA = fmaf(w6, v6, accA); accB = fmaf(w7, v7, accB);
        wsum += (w0 + w1 + w2 + w3) + (w4 + w5 + w6 + w7);
    }
    float acc = accA + accB;
    float o = acc / (wsum + 1e-16f) + b2[lane];
    out2[(size_t)node * 64 + lane] = elu1(o);
}

// ---------------- pool (mean by sorted batch) + fc ----------------
__global__ __launch_bounds__(1024) void k_pool(const float* __restrict__ out2,
                                               const int* __restrict__ batch,
                                               const float* __restrict__ fcW,
                                               const float* __restrict__ fcb,
                                               float* __restrict__ out, int n) {
    __shared__ float sbuf[16][64];
    const int g = blockIdx.x;
    const int lane = threadIdx.x & 63, wv = threadIdx.x >> 6;
    int lo0 = 0, hi0 = n;
    while (lo0 < hi0) { int mid = (lo0 + hi0) >> 1; if (batch[mid] < g) lo0 = mid + 1; else hi0 = mid; }
    int lo1 = lo0, hi1 = n;
    while (lo1 < hi1) { int mid = (lo1 + hi1) >> 1; if (batch[mid] < g + 1) lo1 = mid + 1; else hi1 = mid; }
    float s0 = 0.f, s1 = 0.f;
    int r = lo0 + wv;
    for (; r + 16 < lo1; r += 32) {
        s0 += out2[(size_t)r * 64 + lane];
        s1 += out2[(size_t)(r + 16) * 64 + lane];
    }
    if (r < lo1) s0 += out2[(size_t)r * 64 + lane];
    sbuf[wv][lane] = s0 + s1;
    __syncthreads();
    if (wv == 0) {
        float s = 0.f;
#pragma unroll
        for (int k = 0; k < 16; ++k) s += sbuf[k][lane];
        float cntf = (float)(lo1 - lo0);
        float pooled = s / fmaxf(cntf, 1.f);
        float v = pooled * fcW[lane];
#pragma unroll
        for (int d = 32; d; d >>= 1) v += __shfl_xor(v, d);
        if (lane == 0) out[g] = v + fcb[0];
    }
}

// ---------------- host launcher ----------------
extern "C" void kernel_launch(void* const* d_in, const int* in_sizes, int n_in,
                              void* d_out, int out_size, void* d_ws, size_t ws_size,
                              hipStream_t stream) {
    const float* x      = (const float*)d_in[0];
    const int*   ei     = (const int*)  d_in[1];
    const int*   batch  = (const int*)  d_in[2];
    const float* W1     = (const float*)d_in[3];
    const float* a_src1 = (const float*)d_in[4];
    const float* a_dst1 = (const float*)d_in[5];
    const float* b1     = (const float*)d_in[6];
    const float* W2     = (const float*)d_in[7];
    const float* a_src2 = (const float*)d_in[8];
    const float* a_dst2 = (const float*)d_in[9];
    const float* b2     = (const float*)d_in[10];
    const float* fcW    = (const float*)d_in[11];
    const float* fcb    = (const float*)d_in[12];
    float* out = (float*)d_out;

    const int N = in_sizes[2];
    const int E = in_sizes[1] / 2;
    const int EPAD = E + 8;
    (void)n_in; (void)ws_size;

    char* ws = (char*)d_ws;
    size_t off = 0;
    auto alloc = [&](size_t bytes) -> char* {
        char* p = ws + off;
        off += (bytes + 255) & ~(size_t)255;
        return p;
    };
    int*    cnt    = (int*)   alloc((size_t)N * 4);
    int*    cscan  = (int*)   alloc((size_t)N * 4);
    int*    bsum   = (int*)   alloc((size_t)1024 * 4);
    int*    rank   = (int*)   alloc((size_t)E * 4);
    int*    rowptr = (int*)   alloc((size_t)(N + 1) * 4);
    int*    csr    = (int*)   alloc((size_t)(E + 8) * 4);
    __half* W1p    = (__half*)alloc((size_t)128 * 256 * 2);
    __half* W2p    = (__half*)alloc((size_t)256 * 64 * 2);
    __half* h1h    = (__half*)alloc((size_t)N * 256 * 2);
    __half* x2h    = (__half*)alloc((size_t)N * 256 * 2);
    __half* h2h    = (__half*)alloc((size_t)N * 64 * 2);
    float*  out2   = (float*) alloc((size_t)N * 64 * 4);
    float*  als1   = (float*) alloc((size_t)N * 4 * 4);
    float*  ald1   = (float*) alloc((size_t)N * 4 * 4);
    float*  als2   = (float*) alloc((size_t)N * 4);
    float*  ald2   = (float*) alloc((size_t)N * 4);
    __half* wbuf   = (__half*)alloc((size_t)4 * EPAD * 2);
    __half* selfw  = (__half*)alloc((size_t)N * 4 * 2);
    float*  inv1   = (float*) alloc((size_t)N * 4 * 4);

    hipMemsetAsync(cnt, 0, (size_t)N * 4, stream);
    const int ge = (E + 255) / 256;
    const int nb = (N + 1023) / 1024;
    k_hist<<<ge, 256, 0, stream>>>(ei + E, cnt, rank, E);
    k_scan1<<<nb, 1024, 0, stream>>>(cnt, cscan, bsum, N);
    k_scan2<<<1, 1024, 0, stream>>>(bsum, nb);
    k_scan3<<<nb, 1024, 0, stream>>>(cscan, bsum, rowptr, N);
    k_scatter<<<ge, 256, 0, stream>>>(ei, ei + E, rank, rowptr, csr, E);

    // weight packing (both layers, one launch)
    k_packW<<<24, 256, 0, stream>>>(W1, W1p, W2, W2p);

    // Layer 1
    const int gw = (N / 16 + 3) / 4;
    const int gn4 = (N + 3) / 4;
    k_gemm_mfma<128, 256, true, 4><<<gw, 256, 0, stream>>>(x, W1p, h1h,
                                                           a_src1, a_dst1, als1, ald1, N);
    k_w1<<<gn4, 256, 0, stream>>>(als1, ald1, rowptr, csr, wbuf, selfw, inv1, N, EPAD);
    k_edge1s<<<gn4 * 8, 256, 0, stream>>>(h1h, wbuf, selfw, inv1, rowptr, csr, b1, x2h,
                                          N, EPAD);

    // Layer 2
    k_gemm_mfma<256, 64, false, 1><<<gw, 256, 0, stream>>>(x2h, W2p, h2h,
                                                           a_src2, a_dst2, als2, ald2, N);
    k_edge2<<<gn4, 256, 0, stream>>>(h2h, als2, ald2, rowptr, csr, b2, out2, N);

    // Pool + FC
    k_pool<<<out_size, 1024, 0, stream>>>(out2, batch, fcW, fcb, out, N);
}

// Round 13
// 228.195 us; speedup vs baseline: 1.6562x; 1.6562x over previous
//
#include <hip/hip_runtime.h>
#include <hip/hip_fp16.h>
#include <cstddef>
#include <cstdint>

// N=50000, F_IN=128, HID=64, HEADS=4, E=800000, NG=64
// L1: x(fp32)@W1p -> h1(fp16) + fused als1/ald1 (MFMA, 32 rows/wave); GAT agg (R10 8-wide) -> x2 fp16
// L2: x2@W2p -> h2(fp16) + fused als2/ald2; GAT agg -> out2 fp32
// Pool: segment-mean by sorted batch -> [64,64]; fc -> [64]

#define LOG2E 1.4426950408889634f
__device__ __forceinline__ float lrelu02(float x) { return x >= 0.f ? x : 0.2f * x; }
__device__ __forceinline__ float elu1(float x)    { return x > 0.f ? x : expm1f(x); }
__device__ __forceinline__ float fexp(float x)    { return exp2f(x * LOG2E); }

typedef _Float16 f16x8 __attribute__((ext_vector_type(8)));
typedef float    f32x4 __attribute__((ext_vector_type(4)));

// ---------------- CSR build (by destination) ----------------
__global__ void k_hist(const int* __restrict__ dst, int* __restrict__ cnt,
                       int* __restrict__ rank, int e) {
    int i = blockIdx.x * 256 + threadIdx.x;
    if (i < e) rank[i] = atomicAdd(&cnt[dst[i]], 1);
}

__global__ __launch_bounds__(1024) void k_scan1(const int* __restrict__ cnt,
                                                int* __restrict__ cscan,
                                                int* __restrict__ bsum, int n) {
    __shared__ int ws[16];
    const int t = threadIdx.x, lane = t & 63, wv = t >> 6;
    const int i = blockIdx.x * 1024 + t;
    int v = (i < n) ? cnt[i] : 0;
    int s = v;
#pragma unroll
    for (int d = 1; d < 64; d <<= 1) { int o = __shfl_up(s, d); if (lane >= d) s += o; }
    if (lane == 63) ws[wv] = s;
    __syncthreads();
    if (t < 16) {
        int xx = ws[t];
#pragma unroll
        for (int d = 1; d < 16; d <<= 1) { int o = __shfl_up(xx, d); if (t >= d) xx += o; }
        ws[t] = xx;
        if (t == 15) bsum[blockIdx.x] = xx;
    }
    __syncthreads();
    int incl = s + (wv > 0 ? ws[wv - 1] : 0);
    if (i < n) cscan[i] = incl;
}

__global__ __launch_bounds__(1024) void k_scan2(int* __restrict__ bsum, int nb) {
    __shared__ int ws[16];
    const int t = threadIdx.x, lane = t & 63, wv = t >> 6;
    int v = (t < nb) ? bsum[t] : 0;
    int s = v;
#pragma unroll
    for (int d = 1; d < 64; d <<= 1) { int o = __shfl_up(s, d); if (lane >= d) s += o; }
    if (lane == 63) ws[wv] = s;
    __syncthreads();
    if (t < 16) {
        int xx = ws[t];
#pragma unroll
        for (int d = 1; d < 16; d <<= 1) { int o = __shfl_up(xx, d); if (t >= d) xx += o; }
        ws[t] = xx;
    }
    __syncthreads();
    int incl = s + (wv > 0 ? ws[wv - 1] : 0);
    if (t < nb) bsum[t] = incl - v;   // exclusive
}

__global__ __launch_bounds__(1024) void k_scan3(const int* __restrict__ cscan,
                                                const int* __restrict__ bsum,
                                                int* __restrict__ rowptr, int n) {
    const int i = blockIdx.x * 1024 + threadIdx.x;
    if (i < n) rowptr[i + 1] = cscan[i] + bsum[blockIdx.x];
    if (i == 0) rowptr[0] = 0;
}

__global__ void k_scatter(const int* __restrict__ src, const int* __restrict__ dstArr,
                          const int* __restrict__ rank, const int* __restrict__ rowptr,
                          int* __restrict__ csr, int e) {
    int i = blockIdx.x * 256 + threadIdx.x;
    if (i < e) csr[rowptr[dstArr[i]] + rank[i]] = src[i];
}

// ---------------- W pack (both weights in one launch) ----------------
__device__ __forceinline__ void packOne(const float* __restrict__ W, __half* __restrict__ Bp,
                                        int K, int N, int i) {
    int c = i & 15, q = (i >> 4) & 3, tnt = i >> 6;
    int nt = tnt % (N / 16), t = tnt / (N / 16);
    int k0 = t * 32 + q * 8, col = nt * 16 + c;
    __half tmp[8];
#pragma unroll
    for (int j = 0; j < 8; ++j) tmp[j] = __float2half(W[(size_t)(k0 + j) * N + col]);
    *reinterpret_cast<int4*>(Bp + (size_t)i * 8) = *reinterpret_cast<int4*>(tmp);
}

__global__ void k_packW(const float* __restrict__ W1, __half* __restrict__ B1,
                        const float* __restrict__ W2, __half* __restrict__ B2) {
    int i = blockIdx.x * 256 + threadIdx.x;
    if (i < 4096) packOne(W1, B1, 128, 256, i);
    else if (i < 4096 + 2048) packOne(W2, B2, 256, 64, i - 4096);
}

// ---------------- MFMA GEMM (32 rows/wave, B-fragment reuse) + fused logits ----------------
template <int K, int N, bool AF32, int HEADS_>
__global__ __launch_bounds__(256) void k_gemm_mfma(const void* __restrict__ Av,
                                                   const __half* __restrict__ Bp,
                                                   __half* __restrict__ C,
                                                   const float* __restrict__ a_src,
                                                   const float* __restrict__ a_dst,
                                                   float* __restrict__ als,
                                                   float* __restrict__ ald, int M) {
    constexpr int NT = N / 16, KT = K / 32;
    const int lane = threadIdx.x & 63;
    const int wv = threadIdx.x >> 6;
    const int row0 = (blockIdx.x * 4 + wv) * 32;   // 32 rows per wave (2 MFMA row-tiles)
    if (row0 >= M) return;

    f32x4 acc[2][NT];
#pragma unroll
    for (int r = 0; r < 2; ++r)
#pragma unroll
        for (int nt = 0; nt < NT; ++nt) acc[r][nt] = (f32x4){0.f, 0.f, 0.f, 0.f};

    const __half* Ah = (const __half*)Av;
    const float*  Af = (const float*)Av;
    // clamp second tile's rows to stay in-bounds (results discarded by store guards)
    const int rA = row0 + (lane & 15);
    const int rB = min(row0 + 16 + (lane & 15), M - 1);
    const size_t arowA = (size_t)rA * K + (lane >> 4) * 8;
    const size_t arowB = (size_t)rB * K + (lane >> 4) * 8;
    const __half* Bb = Bp + (size_t)lane * 8;
#pragma unroll
    for (int t = 0; t < KT; ++t) {
        f16x8 a0, a1;
        if constexpr (AF32) {
            float4 u0 = *reinterpret_cast<const float4*>(Af + arowA + t * 32);
            float4 u1 = *reinterpret_cast<const float4*>(Af + arowA + t * 32 + 4);
            float4 u2 = *reinterpret_cast<const float4*>(Af + arowB + t * 32);
            float4 u3 = *reinterpret_cast<const float4*>(Af + arowB + t * 32 + 4);
            a0[0] = (_Float16)u0.x; a0[1] = (_Float16)u0.y;
            a0[2] = (_Float16)u0.z; a0[3] = (_Float16)u0.w;
            a0[4] = (_Float16)u1.x; a0[5] = (_Float16)u1.y;
            a0[6] = (_Float16)u1.z; a0[7] = (_Float16)u1.w;
            a1[0] = (_Float16)u2.x; a1[1] = (_Float16)u2.y;
            a1[2] = (_Float16)u2.z; a1[3] = (_Float16)u2.w;
            a1[4] = (_Float16)u3.x; a1[5] = (_Float16)u3.y;
            a1[6] = (_Float16)u3.z; a1[7] = (_Float16)u3.w;
        } else {
            a0 = *reinterpret_cast<const f16x8*>(Ah + arowA + t * 32);
            a1 = *reinterpret_cast<const f16x8*>(Ah + arowB + t * 32);
        }
#pragma unroll
        for (int nt = 0; nt < NT; ++nt) {
            f16x8 b = *reinterpret_cast<const f16x8*>(Bb + (size_t)(t * NT + nt) * 512);
            acc[0][nt] = __builtin_amdgcn_mfma_f32_16x16x32_f16(a0, b, acc[0][nt], 0, 0, 0);
            acc[1][nt] = __builtin_amdgcn_mfma_f32_16x16x32_f16(a1, b, acc[1][nt], 0, 0, 0);
        }
    }
    const int cl = lane & 15;
    float av[NT], dv[NT];
#pragma unroll
    for (int nt = 0; nt < NT; ++nt) {
        av[nt] = a_src[nt * 16 + cl];
        dv[nt] = a_dst[nt * 16 + cl];
    }
    constexpr int NTH = NT / HEADS_;
#pragma unroll
    for (int r = 0; r < 2; ++r) {
        const int r0 = row0 + r * 16 + (lane >> 4) * 4;
#pragma unroll
        for (int nt = 0; nt < NT; ++nt) {
            int col = nt * 16 + cl;
#pragma unroll
            for (int j = 0; j < 4; ++j)
                if (r0 + j < M)
                    C[(size_t)(r0 + j) * N + col] = __float2half(acc[r][nt][j]);
        }
#pragma unroll
        for (int j = 0; j < 4; ++j) {
#pragma unroll
            for (int h = 0; h < HEADS_; ++h) {
                float ps = 0.f, pd = 0.f;
#pragma unroll
                for (int t = 0; t < NTH; ++t) {
                    ps = fmaf(acc[r][h * NTH + t][j], av[h * NTH + t], ps);
                    pd = fmaf(acc[r][h * NTH + t][j], dv[h * NTH + t], pd);
                }
#pragma unroll
                for (int d = 1; d < 16; d <<= 1) { ps += __shfl_xor(ps, d); pd += __shfl_xor(pd, d); }
                if (cl == 0 && r0 + j < M) {
                    int rr = r0 + j;
                    als[(size_t)rr * HEADS_ + h] = ps;
                    ald[(size_t)rr * HEADS_ + h] = pd;
                }
            }
        }
    }
}

// accumulate 4 halves (float2 = 2x __half2) with scalar weight
__device__ __forceinline__ void h4acc(float2 raw, float w, float& ax, float& ay,
                                      float& az, float& aw2) {
    __half2* q = reinterpret_cast<__half2*>(&raw);
    float2 lo = __half22float2(q[0]), hi = __half22float2(q[1]);
    ax = fmaf(w, lo.x, ax); ay = fmaf(w, lo.y, ay);
    az = fmaf(w, hi.x, az); aw2 = fmaf(w, hi.y, aw2);
}

// ---------------- edge aggregation, layer 1 (R10 masked 8-wide) ----------------
__global__ void k_edge1(const __half* __restrict__ h1, const float* __restrict__ als,
                        const float* __restrict__ ald, const int* __restrict__ rowptr,
                        const int* __restrict__ csr, const float* __restrict__ b1,
                        __half* __restrict__ x2, int n) {
    const int lane = threadIdx.x & 63;
    const int node = (blockIdx.x << 2) + (threadIdx.x >> 6);
    if (node >= n) return;
    const int ch = lane * 4;
    const int e8 = lane & 7, h8 = (lane >> 3) & 3;
    const float adh8 = ald[node * 4 + h8];
    const int head = lane >> 4;
    const int wb = head << 3;
    float axA = 0.f, ayA = 0.f, azA = 0.f, awA = 0.f;
    float axB = 0.f, ayB = 0.f, azB = 0.f, awB = 0.f;
    float wsum = 0.f;
    const int beg = rowptr[node];
    const int deg = rowptr[node + 1] - beg;
    for (int base = 0; base <= deg; base += 8) {
        int s0 = (base + 0 < deg) ? csr[beg + base + 0] : node;
        int s1 = (base + 1 < deg) ? csr[beg + base + 1] : node;
        int s2 = (base + 2 < deg) ? csr[beg + base + 2] : node;
        int s3 = (base + 3 < deg) ? csr[beg + base + 3] : node;
        int s4 = (base + 4 < deg) ? csr[beg + base + 4] : node;
        int s5 = (base + 5 < deg) ? csr[beg + base + 5] : node;
        int s6 = (base + 6 < deg) ? csr[beg + base + 6] : node;
        int s7 = (base + 7 < deg) ? csr[beg + base + 7] : node;
        float2 r0 = *reinterpret_cast<const float2*>(h1 + (size_t)s0 * 256 + ch);
        float2 r1 = *reinterpret_cast<const float2*>(h1 + (size_t)s1 * 256 + ch);
        float2 r2 = *reinterpret_cast<const float2*>(h1 + (size_t)s2 * 256 + ch);
        float2 r3 = *reinterpret_cast<const float2*>(h1 + (size_t)s3 * 256 + ch);
        float2 r4 = *reinterpret_cast<const float2*>(h1 + (size_t)s4 * 256 + ch);
        float2 r5 = *reinterpret_cast<const float2*>(h1 + (size_t)s5 * 256 + ch);
        float2 r6 = *reinterpret_cast<const float2*>(h1 + (size_t)s6 * 256 + ch);
        float2 r7 = *reinterpret_cast<const float2*>(h1 + (size_t)s7 * 256 + ch);
        int se = s0;
        se = (e8 == 1) ? s1 : se; se = (e8 == 2) ? s2 : se; se = (e8 == 3) ? s3 : se;
        se = (e8 == 4) ? s4 : se; se = (e8 == 5) ? s5 : se; se = (e8 == 6) ? s6 : se;
        se = (e8 == 7) ? s7 : se;
        float myw = (base + e8 <= deg)
                        ? fexp(lrelu02(als[(size_t)se * 4 + h8] + adh8)) : 0.f;
        float w0 = __shfl(myw, wb + 0), w1 = __shfl(myw, wb + 1);
        float w2 = __shfl(myw, wb + 2), w3 = __shfl(myw, wb + 3);
        float w4 = __shfl(myw, wb + 4), w5 = __shfl(myw, wb + 5);
        float w6 = __shfl(myw, wb + 6), w7 = __shfl(myw, wb + 7);
        h4acc(r0, w0, axA, ayA, azA, awA);
        h4acc(r1, w1, axB, ayB, azB, awB);
        h4acc(r2, w2, axA, ayA, azA, awA);
        h4acc(r3, w3, axB, ayB, azB, awB);
        h4acc(r4, w4, axA, ayA, azA, awA);
        h4acc(r5, w5, axB, ayB, azB, awB);
        h4acc(r6, w6, axA, ayA, azA, awA);
        h4acc(r7, w7, axB, ayB, azB, awB);
        wsum += ((w0 + w1) + (w2 + w3)) + ((w4 + w5) + (w6 + w7));
    }
    float ax = axA + axB, ay = ayA + ayB, az = azA + azB, aw = awA + awB;
    const float inv = 1.f / (wsum + 1e-16f);
    float4 bv = *reinterpret_cast<const float4*>(b1 + ch);
    __half2 o0 = __floats2half2_rn(elu1(ax * inv + bv.x), elu1(ay * inv + bv.y));
    __half2 o1 = __floats2half2_rn(elu1(az * inv + bv.z), elu1(aw * inv + bv.w));
    int2 p;
    p.x = *reinterpret_cast<int*>(&o0);
    p.y = *reinterpret_cast<int*>(&o1);
    *reinterpret_cast<int2*>(x2 + (size_t)node * 256 + ch) = p;
}

// ---------------- edge aggregation, layer 2 (R10 masked 8-wide) ----------------
__global__ void k_edge2(const __half* __restrict__ h2, const float* __restrict__ als,
                        const float* __restrict__ ald, const int* __restrict__ rowptr,
                        const int* __restrict__ csr, const float* __restrict__ b2,
                        float* __restrict__ out2, int n) {
    const int lane = threadIdx.x & 63;
    const int node = (blockIdx.x << 2) + (threadIdx.x >> 6);
    if (node >= n) return;
    const int e8 = lane & 7;
    const float adl = ald[node];
    float accA = 0.f, accB = 0.f, wsum = 0.f;
    const int beg = rowptr[node];
    const int deg = rowptr[node + 1] - beg;
    for (int base = 0; base <= deg; base += 8) {
        int s0 = (base + 0 < deg) ? csr[beg + base + 0] : node;
        int s1 = (base + 1 < deg) ? csr[beg + base + 1] : node;
        int s2 = (base + 2 < deg) ? csr[beg + base + 2] : node;
        int s3 = (base + 3 < deg) ? csr[beg + base + 3] : node;
        int s4 = (base + 4 < deg) ? csr[beg + base + 4] : node;
        int s5 = (base + 5 < deg) ? csr[beg + base + 5] : node;
        int s6 = (base + 6 < deg) ? csr[beg + base + 6] : node;
        int s7 = (base + 7 < deg) ? csr[beg + base + 7] : node;
        float v0 = __half2float(h2[(size_t)s0 * 64 + lane]);
        float v1 = __half2float(h2[(size_t)s1 * 64 + lane]);
        float v2 = __half2float(h2[(size_t)s2 * 64 + lane]);
        float v3 = __half2float(h2[(size_t)s3 * 64 + lane]);
        float v4 = __half2float(h2[(size_t)s4 * 64 + lane]);
        float v5 = __half2float(h2[(size_t)s5 * 64 + lane]);
        float v6 = __half2float(h2[(size_t)s6 * 64 + lane]);
        float v7 = __half2float(h2[(size_t)s7 * 64 + lane]);
        int se = s0;
        se = (e8 == 1) ? s1 : se; se = (e8 == 2) ? s2 : se; se = (e8 == 3) ? s3 : se;
        se = (e8 == 4) ? s4 : se; se = (e8 == 5) ? s5 : se; se = (e8 == 6) ? s6 : se;
        se = (e8 == 7) ? s7 : se;
        float myw = (base + e8 <= deg) ? fexp(lrelu02(als[se] + adl)) : 0.f;
        float w0 = __shfl(myw, 0), w1 = __shfl(myw, 1), w2 = __shfl(myw, 2), w3 = __shfl(myw, 3);
        float w4 = __shfl(myw, 4), w5 = __shfl(myw, 5), w6 = __shfl(myw, 6), w7 = __shfl(myw, 7);
        accA = fmaf(w0, v0, accA); accB = fmaf(w1, v1, accB);
        accA = fmaf(w2, v2, accA); accB = fmaf(w3, v3, accB);
        accA = fmaf(w4, v4, accA); accB = fmaf(w5, v5, accB);
        accA = fmaf(w6, v6, accA); accB = fmaf(w7, v7, accB);
        wsum += (w0 + w1 + w2 + w3) + (w4 + w5 + w6 + w7);
    }
    float acc = accA + accB;
    float o = acc / (wsum + 1e-16f) + b2[lane];
    out2[(size_t)node * 64 + lane] = elu1(o);
}

// ---------------- pool (mean by sorted batch) + fc ----------------
__global__ __launch_bounds__(1024) void k_pool(const float* __restrict__ out2,
                                               const int* __restrict__ batch,
                                               const float* __restrict__ fcW,
                                               const float* __restrict__ fcb,
                                               float* __restrict__ out, int n) {
    __shared__ float sbuf[16][64];
    const int g = blockIdx.x;
    const int lane = threadIdx.x & 63, wv = threadIdx.x >> 6;
    int lo0 = 0, hi0 = n;
    while (lo0 < hi0) { int mid = (lo0 + hi0) >> 1; if (batch[mid] < g) lo0 = mid + 1; else hi0 = mid; }
    int lo1 = lo0, hi1 = n;
    while (lo1 < hi1) { int mid = (lo1 + hi1) >> 1; if (batch[mid] < g + 1) lo1 = mid + 1; else hi1 = mid; }
    float s0 = 0.f, s1 = 0.f;
    int r = lo0 + wv;
    for (; r + 16 < lo1; r += 32) {
        s0 += out2[(size_t)r * 64 + lane];
        s1 += out2[(size_t)(r + 16) * 64 + lane];
    }
    if (r < lo1) s0 += out2[(size_t)r * 64 + lane];
    sbuf[wv][lane] = s0 + s1;
    __syncthreads();
    if (wv == 0) {
        float s = 0.f;
#pragma unroll
        for (int k = 0; k < 16; ++k) s += sbuf[k][lane];
        float cntf = (float)(lo1 - lo0);
        float pooled = s / fmaxf(cntf, 1.f);
        float v = pooled * fcW[lane];
#pragma unroll
        for (int d = 32; d; d >>= 1) v += __shfl_xor(v, d);
        if (lane == 0) out[g] = v + fcb[0];
    }
}

// ---------------- host launcher ----------------
extern "C" void kernel_launch(void* const* d_in, const int* in_sizes, int n_in,
                              void* d_out, int out_size, void* d_ws, size_t ws_size,
                              hipStream_t stream) {
    const float* x      = (const float*)d_in[0];
    const int*   ei     = (const int*)  d_in[1];
    const int*   batch  = (const int*)  d_in[2];
    const float* W1     = (const float*)d_in[3];
    const float* a_src1 = (const float*)d_in[4];
    const float* a_dst1 = (const float*)d_in[5];
    const float* b1     = (const float*)d_in[6];
    const float* W2     = (const float*)d_in[7];
    const float* a_src2 = (const float*)d_in[8];
    const float* a_dst2 = (const float*)d_in[9];
    const float* b2     = (const float*)d_in[10];
    const float* fcW    = (const float*)d_in[11];
    const float* fcb    = (const float*)d_in[12];
    float* out = (float*)d_out;

    const int N = in_sizes[2];
    const int E = in_sizes[1] / 2;
    (void)n_in; (void)ws_size;

    char* ws = (char*)d_ws;
    size_t off = 0;
    auto alloc = [&](size_t bytes) -> char* {
        char* p = ws + off;
        off += (bytes + 255) & ~(size_t)255;
        return p;
    };
    int*    cnt    = (int*)   alloc((size_t)N * 4);
    int*    cscan  = (int*)   alloc((size_t)N * 4);
    int*    bsum   = (int*)   alloc((size_t)1024 * 4);
    int*    rank   = (int*)   alloc((size_t)E * 4);
    int*    rowptr = (int*)   alloc((size_t)(N + 1) * 4);
    int*    csr    = (int*)   alloc((size_t)(E + 8) * 4);
    __half* W1p    = (__half*)alloc((size_t)128 * 256 * 2);
    __half* W2p    = (__half*)alloc((size_t)256 * 64 * 2);
    __half* h1h    = (__half*)alloc((size_t)N * 256 * 2);
    __half* x2h    = (__half*)alloc((size_t)N * 256 * 2);
    __half* h2h    = (__half*)alloc((size_t)N * 64 * 2);
    float*  out2   = (float*) alloc((size_t)N * 64 * 4);
    float*  als1   = (float*) alloc((size_t)N * 4 * 4);
    float*  ald1   = (float*) alloc((size_t)N * 4 * 4);
    float*  als2   = (float*) alloc((size_t)N * 4);
    float*  ald2   = (float*) alloc((size_t)N * 4);

    hipMemsetAsync(cnt, 0, (size_t)N * 4, stream);
    const int ge = (E + 255) / 256;
    const int nb = (N + 1023) / 1024;
    k_hist<<<ge, 256, 0, stream>>>(ei + E, cnt, rank, E);
    k_scan1<<<nb, 1024, 0, stream>>>(cnt, cscan, bsum, N);
    k_scan2<<<1, 1024, 0, stream>>>(bsum, nb);
    k_scan3<<<nb, 1024, 0, stream>>>(cscan, bsum, rowptr, N);
    k_scatter<<<ge, 256, 0, stream>>>(ei, ei + E, rank, rowptr, csr, E);

    // weight packing (both layers, one launch)
    k_packW<<<24, 256, 0, stream>>>(W1, W1p, W2, W2p);

    // Layer 1: MFMA GEMM [N,128](fp32 A)@[128,256] -> fp16 h1 + fused als1/ald1
    const int gw = ((N + 31) / 32 + 3) / 4;   // 32 rows per wave, 4 waves per block
    const int gn4 = (N + 3) / 4;
    k_gemm_mfma<128, 256, true, 4><<<gw, 256, 0, stream>>>(x, W1p, h1h,
                                                           a_src1, a_dst1, als1, ald1, N);
    k_edge1<<<gn4, 256, 0, stream>>>(h1h, als1, ald1, rowptr, csr, b1, x2h, N);

    // Layer 2: MFMA GEMM [N,256]@[256,64] -> fp16 h2 + fused als2/ald2
    k_gemm_mfma<256, 64, false, 1><<<gw, 256, 0, stream>>>(x2h, W2p, h2h,
                                                           a_src2, a_dst2, als2, ald2, N);
    k_edge2<<<gn4, 256, 0, stream>>>(h2h, als2, ald2, rowptr, csr, b2, out2, N);

    // Pool + FC
    k_pool<<<out_size, 1024, 0, stream>>>(out2, batch, fcW, fcb, out, N);
}

// Round 14
// 216.482 us; speedup vs baseline: 1.7459x; 1.0541x over previous
//
#include <hip/hip_runtime.h>
#include <hip/hip_fp16.h>
#include <cstddef>
#include <cstdint>

// N=50000, F_IN=128, HID=64, HEADS=4, E=800000, NG=64
// L1: x(fp32)@W1p -> h1(fp16) + fused als1/ald1 (MFMA epilogue); GAT agg (8-wide masked) -> x2 fp16
// L2: x2@W2p -> h2(fp16) + fused als2/ald2; GAT agg -> out2 fp32
// Pool: segment-mean by sorted batch -> [64,64]; fc -> [64]
// R14 = R10 champion set (edge kernels + 16-row GEMM) with packW folded into k_hist.

#define LOG2E 1.4426950408889634f
__device__ __forceinline__ float lrelu02(float x) { return x >= 0.f ? x : 0.2f * x; }
__device__ __forceinline__ float elu1(float x)    { return x > 0.f ? x : expm1f(x); }
__device__ __forceinline__ float fexp(float x)    { return exp2f(x * LOG2E); }

typedef _Float16 f16x8 __attribute__((ext_vector_type(8)));
typedef float    f32x4 __attribute__((ext_vector_type(4)));

// ---------------- W pack helper ----------------
__device__ __forceinline__ void packOne(const float* __restrict__ W, __half* __restrict__ Bp,
                                        int K, int N, int i) {
    int c = i & 15, q = (i >> 4) & 3, tnt = i >> 6;
    int nt = tnt % (N / 16), t = tnt / (N / 16);
    int k0 = t * 32 + q * 8, col = nt * 16 + c;
    __half tmp[8];
#pragma unroll
    for (int j = 0; j < 8; ++j) tmp[j] = __float2half(W[(size_t)(k0 + j) * N + col]);
    *reinterpret_cast<int4*>(Bp + (size_t)i * 8) = *reinterpret_cast<int4*>(tmp);
}

// ---------------- CSR pass 1 (+ weight packing in leading blocks) ----------------
// blocks [0,24): pack W1/W2 fragments; blocks [24, ...): histogram + per-edge rank.
__global__ void k_hist(const int* __restrict__ dst, int* __restrict__ cnt,
                       int* __restrict__ rank, int e,
                       const float* __restrict__ W1, __half* __restrict__ B1,
                       const float* __restrict__ W2, __half* __restrict__ B2) {
    if (blockIdx.x < 24) {
        int i = blockIdx.x * 256 + threadIdx.x;
        if (i < 4096) packOne(W1, B1, 128, 256, i);
        else if (i < 4096 + 2048) packOne(W2, B2, 256, 64, i - 4096);
        return;
    }
    int i = (blockIdx.x - 24) * 256 + threadIdx.x;
    if (i < e) rank[i] = atomicAdd(&cnt[dst[i]], 1);
}

__global__ __launch_bounds__(1024) void k_scan1(const int* __restrict__ cnt,
                                                int* __restrict__ cscan,
                                                int* __restrict__ bsum, int n) {
    __shared__ int ws[16];
    const int t = threadIdx.x, lane = t & 63, wv = t >> 6;
    const int i = blockIdx.x * 1024 + t;
    int v = (i < n) ? cnt[i] : 0;
    int s = v;
#pragma unroll
    for (int d = 1; d < 64; d <<= 1) { int o = __shfl_up(s, d); if (lane >= d) s += o; }
    if (lane == 63) ws[wv] = s;
    __syncthreads();
    if (t < 16) {
        int xx = ws[t];
#pragma unroll
        for (int d = 1; d < 16; d <<= 1) { int o = __shfl_up(xx, d); if (t >= d) xx += o; }
        ws[t] = xx;
        if (t == 15) bsum[blockIdx.x] = xx;
    }
    __syncthreads();
    int incl = s + (wv > 0 ? ws[wv - 1] : 0);
    if (i < n) cscan[i] = incl;
}

__global__ __launch_bounds__(1024) void k_scan2(int* __restrict__ bsum, int nb) {
    __shared__ int ws[16];
    const int t = threadIdx.x, lane = t & 63, wv = t >> 6;
    int v = (t < nb) ? bsum[t] : 0;
    int s = v;
#pragma unroll
    for (int d = 1; d < 64; d <<= 1) { int o = __shfl_up(s, d); if (lane >= d) s += o; }
    if (lane == 63) ws[wv] = s;
    __syncthreads();
    if (t < 16) {
        int xx = ws[t];
#pragma unroll
        for (int d = 1; d < 16; d <<= 1) { int o = __shfl_up(xx, d); if (t >= d) xx += o; }
        ws[t] = xx;
    }
    __syncthreads();
    int incl = s + (wv > 0 ? ws[wv - 1] : 0);
    if (t < nb) bsum[t] = incl - v;   // exclusive
}

__global__ __launch_bounds__(1024) void k_scan3(const int* __restrict__ cscan,
                                                const int* __restrict__ bsum,
                                                int* __restrict__ rowptr, int n) {
    const int i = blockIdx.x * 1024 + threadIdx.x;
    if (i < n) rowptr[i + 1] = cscan[i] + bsum[blockIdx.x];
    if (i == 0) rowptr[0] = 0;
}

__global__ void k_scatter(const int* __restrict__ src, const int* __restrict__ dstArr,
                          const int* __restrict__ rank, const int* __restrict__ rowptr,
                          int* __restrict__ csr, int e) {
    int i = blockIdx.x * 256 + threadIdx.x;
    if (i < e) csr[rowptr[dstArr[i]] + rank[i]] = src[i];
}

// ---------------- MFMA GEMM (16 rows/wave) + fused attention logits ----------------
template <int K, int N, bool AF32, int HEADS_>
__global__ __launch_bounds__(256) void k_gemm_mfma(const void* __restrict__ Av,
                                                   const __half* __restrict__ Bp,
                                                   __half* __restrict__ C,
                                                   const float* __restrict__ a_src,
                                                   const float* __restrict__ a_dst,
                                                   float* __restrict__ als,
                                                   float* __restrict__ ald, int M) {
    constexpr int NT = N / 16, KT = K / 32;
    const int lane = threadIdx.x & 63;
    const int wv = threadIdx.x >> 6;
    const int row0 = (blockIdx.x * 4 + wv) * 16;
    if (row0 >= M) return;

    f32x4 acc[NT];
#pragma unroll
    for (int nt = 0; nt < NT; ++nt) acc[nt] = (f32x4){0.f, 0.f, 0.f, 0.f};

    const __half* Ah = (const __half*)Av;
    const float*  Af = (const float*)Av;
    const size_t arow = (size_t)(row0 + (lane & 15)) * K + (lane >> 4) * 8;
    const __half* Bb = Bp + (size_t)lane * 8;
#pragma unroll
    for (int t = 0; t < KT; ++t) {
        f16x8 a;
        if constexpr (AF32) {
            float4 u0 = *reinterpret_cast<const float4*>(Af + arow + t * 32);
            float4 u1 = *reinterpret_cast<const float4*>(Af + arow + t * 32 + 4);
            a[0] = (_Float16)u0.x; a[1] = (_Float16)u0.y;
            a[2] = (_Float16)u0.z; a[3] = (_Float16)u0.w;
            a[4] = (_Float16)u1.x; a[5] = (_Float16)u1.y;
            a[6] = (_Float16)u1.z; a[7] = (_Float16)u1.w;
        } else {
            a = *reinterpret_cast<const f16x8*>(Ah + arow + t * 32);
        }
#pragma unroll
        for (int nt = 0; nt < NT; ++nt) {
            f16x8 b = *reinterpret_cast<const f16x8*>(Bb + (size_t)(t * NT + nt) * 512);
            acc[nt] = __builtin_amdgcn_mfma_f32_16x16x32_f16(a, b, acc[nt], 0, 0, 0);
        }
    }
    const int r0 = row0 + (lane >> 4) * 4;
    const int cl = lane & 15;
#pragma unroll
    for (int nt = 0; nt < NT; ++nt) {
        int col = nt * 16 + cl;
#pragma unroll
        for (int j = 0; j < 4; ++j)
            C[(size_t)(r0 + j) * N + col] = __float2half(acc[nt][j]);
    }
    float av[NT], dv[NT];
#pragma unroll
    for (int nt = 0; nt < NT; ++nt) {
        av[nt] = a_src[nt * 16 + cl];
        dv[nt] = a_dst[nt * 16 + cl];
    }
    constexpr int NTH = NT / HEADS_;
#pragma unroll
    for (int j = 0; j < 4; ++j) {
#pragma unroll
        for (int h = 0; h < HEADS_; ++h) {
            float ps = 0.f, pd = 0.f;
#pragma unroll
            for (int t = 0; t < NTH; ++t) {
                ps = fmaf(acc[h * NTH + t][j], av[h * NTH + t], ps);
                pd = fmaf(acc[h * NTH + t][j], dv[h * NTH + t], pd);
            }
#pragma unroll
            for (int d = 1; d < 16; d <<= 1) { ps += __shfl_xor(ps, d); pd += __shfl_xor(pd, d); }
            if (cl == 0) {
                int r = r0 + j;
                als[(size_t)r * HEADS_ + h] = ps;
                ald[(size_t)r * HEADS_ + h] = pd;
            }
        }
    }
}

// accumulate 4 halves (float2 = 2x __half2) with scalar weight
__device__ __forceinline__ void h4acc(float2 raw, float w, float& ax, float& ay,
                                      float& az, float& aw2) {
    __half2* q = reinterpret_cast<__half2*>(&raw);
    float2 lo = __half22float2(q[0]), hi = __half22float2(q[1]);
    ax = fmaf(w, lo.x, ax); ay = fmaf(w, lo.y, ay);
    az = fmaf(w, hi.x, az); aw2 = fmaf(w, hi.y, aw2);
}

// ---------------- edge aggregation, layer 1 (masked 8-wide, virtual self-loop) ----------------
__global__ void k_edge1(const __half* __restrict__ h1, const float* __restrict__ als,
                        const float* __restrict__ ald, const int* __restrict__ rowptr,
                        const int* __restrict__ csr, const float* __restrict__ b1,
                        __half* __restrict__ x2, int n) {
    const int lane = threadIdx.x & 63;
    const int node = (blockIdx.x << 2) + (threadIdx.x >> 6);
    if (node >= n) return;
    const int ch = lane * 4;
    const int e8 = lane & 7, h8 = (lane >> 3) & 3;
    const float adh8 = ald[node * 4 + h8];
    const int head = lane >> 4;
    const int wb = head << 3;
    float axA = 0.f, ayA = 0.f, azA = 0.f, awA = 0.f;
    float axB = 0.f, ayB = 0.f, azB = 0.f, awB = 0.f;
    float wsum = 0.f;
    const int beg = rowptr[node];
    const int deg = rowptr[node + 1] - beg;
    for (int base = 0; base <= deg; base += 8) {
        int s0 = (base + 0 < deg) ? csr[beg + base + 0] : node;
        int s1 = (base + 1 < deg) ? csr[beg + base + 1] : node;
        int s2 = (base + 2 < deg) ? csr[beg + base + 2] : node;
        int s3 = (base + 3 < deg) ? csr[beg + base + 3] : node;
        int s4 = (base + 4 < deg) ? csr[beg + base + 4] : node;
        int s5 = (base + 5 < deg) ? csr[beg + base + 5] : node;
        int s6 = (base + 6 < deg) ? csr[beg + base + 6] : node;
        int s7 = (base + 7 < deg) ? csr[beg + base + 7] : node;
        float2 r0 = *reinterpret_cast<const float2*>(h1 + (size_t)s0 * 256 + ch);
        float2 r1 = *reinterpret_cast<const float2*>(h1 + (size_t)s1 * 256 + ch);
        float2 r2 = *reinterpret_cast<const float2*>(h1 + (size_t)s2 * 256 + ch);
        float2 r3 = *reinterpret_cast<const float2*>(h1 + (size_t)s3 * 256 + ch);
        float2 r4 = *reinterpret_cast<const float2*>(h1 + (size_t)s4 * 256 + ch);
        float2 r5 = *reinterpret_cast<const float2*>(h1 + (size_t)s5 * 256 + ch);
        float2 r6 = *reinterpret_cast<const float2*>(h1 + (size_t)s6 * 256 + ch);
        float2 r7 = *reinterpret_cast<const float2*>(h1 + (size_t)s7 * 256 + ch);
        int se = s0;
        se = (e8 == 1) ? s1 : se; se = (e8 == 2) ? s2 : se; se = (e8 == 3) ? s3 : se;
        se = (e8 == 4) ? s4 : se; se = (e8 == 5) ? s5 : se; se = (e8 == 6) ? s6 : se;
        se = (e8 == 7) ? s7 : se;
        float myw = (base + e8 <= deg)
                        ? fexp(lrelu02(als[(size_t)se * 4 + h8] + adh8)) : 0.f;
        float w0 = __shfl(myw, wb + 0), w1 = __shfl(myw, wb + 1);
        float w2 = __shfl(myw, wb + 2), w3 = __shfl(myw, wb + 3);
        float w4 = __shfl(myw, wb + 4), w5 = __shfl(myw, wb + 5);
        float w6 = __shfl(myw, wb + 6), w7 = __shfl(myw, wb + 7);
        h4acc(r0, w0, axA, ayA, azA, awA);
        h4acc(r1, w1, axB, ayB, azB, awB);
        h4acc(r2, w2, axA, ayA, azA, awA);
        h4acc(r3, w3, axB, ayB, azB, awB);
        h4acc(r4, w4, axA, ayA, azA, awA);
        h4acc(r5, w5, axB, ayB, azB, awB);
        h4acc(r6, w6, axA, ayA, azA, awA);
        h4acc(r7, w7, axB, ayB, azB, awB);
        wsum += ((w0 + w1) + (w2 + w3)) + ((w4 + w5) + (w6 + w7));
    }
    float ax = axA + axB, ay = ayA + ayB, az = azA + azB, aw = awA + awB;
    const float inv = 1.f / (wsum + 1e-16f);
    float4 bv = *reinterpret_cast<const float4*>(b1 + ch);
    __half2 o0 = __floats2half2_rn(elu1(ax * inv + bv.x), elu1(ay * inv + bv.y));
    __half2 o1 = __floats2half2_rn(elu1(az * inv + bv.z), elu1(aw * inv + bv.w));
    int2 p;
    p.x = *reinterpret_cast<int*>(&o0);
    p.y = *reinterpret_cast<int*>(&o1);
    *reinterpret_cast<int2*>(x2 + (size_t)node * 256 + ch) = p;
}

// ---------------- edge aggregation, layer 2 (masked 8-wide) ----------------
__global__ void k_edge2(const __half* __restrict__ h2, const float* __restrict__ als,
                        const float* __restrict__ ald, const int* __restrict__ rowptr,
                        const int* __restrict__ csr, const float* __restrict__ b2,
                        float* __restrict__ out2, int n) {
    const int lane = threadIdx.x & 63;
    const int node = (blockIdx.x << 2) + (threadIdx.x >> 6);
    if (node >= n) return;
    const int e8 = lane & 7;
    const float adl = ald[node];
    float accA = 0.f, accB = 0.f, wsum = 0.f;
    const int beg = rowptr[node];
    const int deg = rowptr[node + 1] - beg;
    for (int base = 0; base <= deg; base += 8) {
        int s0 = (base + 0 < deg) ? csr[beg + base + 0] : node;
        int s1 = (base + 1 < deg) ? csr[beg + base + 1] : node;
        int s2 = (base + 2 < deg) ? csr[beg + base + 2] : node;
        int s3 = (base + 3 < deg) ? csr[beg + base + 3] : node;
        int s4 = (base + 4 < deg) ? csr[beg + base + 4] : node;
        int s5 = (base + 5 < deg) ? csr[beg + base + 5] : node;
        int s6 = (base + 6 < deg) ? csr[beg + base + 6] : node;
        int s7 = (base + 7 < deg) ? csr[beg + base + 7] : node;
        float v0 = __half2float(h2[(size_t)s0 * 64 + lane]);
        float v1 = __half2float(h2[(size_t)s1 * 64 + lane]);
        float v2 = __half2float(h2[(size_t)s2 * 64 + lane]);
        float v3 = __half2float(h2[(size_t)s3 * 64 + lane]);
        float v4 = __half2float(h2[(size_t)s4 * 64 + lane]);
        float v5 = __half2float(h2[(size_t)s5 * 64 + lane]);
        float v6 = __half2float(h2[(size_t)s6 * 64 + lane]);
        float v7 = __half2float(h2[(size_t)s7 * 64 + lane]);
        int se = s0;
        se = (e8 == 1) ? s1 : se; se = (e8 == 2) ? s2 : se; se = (e8 == 3) ? s3 : se;
        se = (e8 == 4) ? s4 : se; se = (e8 == 5) ? s5 : se; se = (e8 == 6) ? s6 : se;
        se = (e8 == 7) ? s7 : se;
        float myw = (base + e8 <= deg) ? fexp(lrelu02(als[se] + adl)) : 0.f;
        float w0 = __shfl(myw, 0), w1 = __shfl(myw, 1), w2 = __shfl(myw, 2), w3 = __shfl(myw, 3);
        float w4 = __shfl(myw, 4), w5 = __shfl(myw, 5), w6 = __shfl(myw, 6), w7 = __shfl(myw, 7);
        accA = fmaf(w0, v0, accA); accB = fmaf(w1, v1, accB);
        accA = fmaf(w2, v2, accA); accB = fmaf(w3, v3, accB);
        accA = fmaf(w4, v4, accA); accB = fmaf(w5, v5, accB);
        accA = fmaf(w6, v6, accA); accB = fmaf(w7, v7, accB);
        wsum += (w0 + w1 + w2 + w3) + (w4 + w5 + w6 + w7);
    }
    float acc = accA + accB;
    float o = acc / (wsum + 1e-16f) + b2[lane];
    out2[(size_t)node * 64 + lane] = elu1(o);
}

// ---------------- pool (mean by sorted batch) + fc ----------------
__global__ __launch_bounds__(1024) void k_pool(const float* __restrict__ out2,
                                               const int* __restrict__ batch,
                                               const float* __restrict__ fcW,
                                               const float* __restrict__ fcb,
                                               float* __restrict__ out, int n) {
    __shared__ float sbuf[16][64];
    const int g = blockIdx.x;
    const int lane = threadIdx.x & 63, wv = threadIdx.x >> 6;
    int lo0 = 0, hi0 = n;
    while (lo0 < hi0) { int mid = (lo0 + hi0) >> 1; if (batch[mid] < g) lo0 = mid + 1; else hi0 = mid; }
    int lo1 = lo0, hi1 = n;
    while (lo1 < hi1) { int mid = (lo1 + hi1) >> 1; if (batch[mid] < g + 1) lo1 = mid + 1; else hi1 = mid; }
    float s0 = 0.f, s1 = 0.f;
    int r = lo0 + wv;
    for (; r + 16 < lo1; r += 32) {
        s0 += out2[(size_t)r * 64 + lane];
        s1 += out2[(size_t)(r + 16) * 64 + lane];
    }
    if (r < lo1) s0 += out2[(size_t)r * 64 + lane];
    sbuf[wv][lane] = s0 + s1;
    __syncthreads();
    if (wv == 0) {
        float s = 0.f;
#pragma unroll
        for (int k = 0; k < 16; ++k) s += sbuf[k][lane];
        float cntf = (float)(lo1 - lo0);
        float pooled = s / fmaxf(cntf, 1.f);
        float v = pooled * fcW[lane];
#pragma unroll
        for (int d = 32; d; d >>= 1) v += __shfl_xor(v, d);
        if (lane == 0) out[g] = v + fcb[0];
    }
}

// ---------------- host launcher ----------------
extern "C" void kernel_launch(void* const* d_in, const int* in_sizes, int n_in,
                              void* d_out, int out_size, void* d_ws, size_t ws_size,
                              hipStream_t stream) {
    const float* x      = (const float*)d_in[0];
    const int*   ei     = (const int*)  d_in[1];
    const int*   batch  = (const int*)  d_in[2];
    const float* W1     = (const float*)d_in[3];
    const float* a_src1 = (const float*)d_in[4];
    const float* a_dst1 = (const float*)d_in[5];
    const float* b1     = (const float*)d_in[6];
    const float* W2     = (const float*)d_in[7];
    const float* a_src2 = (const float*)d_in[8];
    const float* a_dst2 = (const float*)d_in[9];
    const float* b2     = (const float*)d_in[10];
    const float* fcW    = (const float*)d_in[11];
    const float* fcb    = (const float*)d_in[12];
    float* out = (float*)d_out;

    const int N = in_sizes[2];
    const int E = in_sizes[1] / 2;
    (void)n_in; (void)ws_size;

    char* ws = (char*)d_ws;
    size_t off = 0;
    auto alloc = [&](size_t bytes) -> char* {
        char* p = ws + off;
        off += (bytes + 255) & ~(size_t)255;
        return p;
    };
    int*    cnt    = (int*)   alloc((size_t)N * 4);
    int*    cscan  = (int*)   alloc((size_t)N * 4);
    int*    bsum   = (int*)   alloc((size_t)1024 * 4);
    int*    rank   = (int*)   alloc((size_t)E * 4);
    int*    rowptr = (int*)   alloc((size_t)(N + 1) * 4);
    int*    csr    = (int*)   alloc((size_t)(E + 8) * 4);
    __half* W1p    = (__half*)alloc((size_t)128 * 256 * 2);
    __half* W2p    = (__half*)alloc((size_t)256 * 64 * 2);
    __half* h1h    = (__half*)alloc((size_t)N * 256 * 2);
    __half* x2h    = (__half*)alloc((size_t)N * 256 * 2);
    __half* h2h    = (__half*)alloc((size_t)N * 64 * 2);
    float*  out2   = (float*) alloc((size_t)N * 64 * 4);
    float*  als1   = (float*) alloc((size_t)N * 4 * 4);
    float*  ald1   = (float*) alloc((size_t)N * 4 * 4);
    float*  als2   = (float*) alloc((size_t)N * 4);
    float*  ald2   = (float*) alloc((size_t)N * 4);

    hipMemsetAsync(cnt, 0, (size_t)N * 4, stream);
    const int ge = (E + 255) / 256;
    const int nb = (N + 1023) / 1024;
    k_hist<<<ge + 24, 256, 0, stream>>>(ei + E, cnt, rank, E, W1, W1p, W2, W2p);
    k_scan1<<<nb, 1024, 0, stream>>>(cnt, cscan, bsum, N);
    k_scan2<<<1, 1024, 0, stream>>>(bsum, nb);
    k_scan3<<<nb, 1024, 0, stream>>>(cscan, bsum, rowptr, N);
    k_scatter<<<ge, 256, 0, stream>>>(ei, ei + E, rank, rowptr, csr, E);

    // Layer 1: MFMA GEMM [N,128](fp32 A)@[128,256] -> fp16 h1 + fused als1/ald1
    const int gw = (N / 16 + 3) / 4;
    const int gn4 = (N + 3) / 4;
    k_gemm_mfma<128, 256, true, 4><<<gw, 256, 0, stream>>>(x, W1p, h1h,
                                                           a_src1, a_dst1, als1, ald1, N);
    k_edge1<<<gn4, 256, 0, stream>>>(h1h, als1, ald1, rowptr, csr, b1, x2h, N);

    // Layer 2: MFMA GEMM [N,256]@[256,64] -> fp16 h2 + fused als2/ald2
    k_gemm_mfma<256, 64, false, 1><<<gw, 256, 0, stream>>>(x2h, W2p, h2h,
                                                           a_src2, a_dst2, als2, ald2, N);
    k_edge2<<<gn4, 256, 0, stream>>>(h2h, als2, ald2, rowptr, csr, b2, out2, N);

    // Pool + FC
    k_pool<<<out_size, 1024, 0, stream>>>(out2, batch, fcW, fcb, out, N);
}